// Round 4
// baseline (450.002 us; speedup 1.0000x reference)
//
#include <hip/hip_runtime.h>

#define NSHOTS 4
#define NT     512
#define NZ     256
#define NX     256
#define NRECS  128

static constexpr float DTf    = 0.001f;
static constexpr float INVDH2 = 1.0f / (10.0f * 10.0f);

#define KSTEPS 8                  // fused steps per phase
#define TZ     8                  // interior z rows per tile
#define XI     32                 // interior x per tile
#define HALOX  16                 // (64-XI)/2 >= KSTEPS
#define EXTZ   (TZ + 2*KSTEPS)    // 24 ext rows, all in registers
#define NPR    (EXTZ/2)           // 12 v2f row-pairs per thread
#define NTZT   (NZ/TZ)            // 32
#define NTXT   (NX/XI)            // 8
#define NTILES (NSHOTS*NTZT*NTXT) // 1024 waves, 4/CU (1/SIMD), co-resident
#define NPHASE (NT/KSTEPS)        // 64
#define LSTRIDE 32                // dwords between flags (128 B)

typedef float v2f __attribute__((ext_vector_type(2)));

// lane i <- lane i-1 (left x-neighbor); OOB lane 0 reads 0 (bound_ctrl=1)
__device__ __forceinline__ float nbr_left(float v) {
  return __int_as_float(__builtin_amdgcn_update_dpp(
      0, __float_as_int(v), 0x138 /*WAVE_SHR1*/, 0xf, 0xf, true));
}
// lane i <- lane i+1 (right x-neighbor); OOB lane 63 reads 0
__device__ __forceinline__ float nbr_right(float v) {
  return __int_as_float(__builtin_amdgcn_update_dpp(
      0, __float_as_int(v), 0x130 /*WAVE_SHL1*/, 0xf, 0xf, true));
}

// LLC-coherent (cross-XCD) access: agent-scope relaxed -> sc0 sc1.
__device__ __forceinline__ float gload(const float* p) {
  return __hip_atomic_load(p, __ATOMIC_RELAXED, __HIP_MEMORY_SCOPE_AGENT);
}
__device__ __forceinline__ void gstore(float* p, float v) {
  __hip_atomic_store(p, v, __ATOMIC_RELAXED, __HIP_MEMORY_SCOPE_AGENT);
}
__device__ __forceinline__ unsigned fload(const unsigned* p) {
  return __hip_atomic_load(p, __ATOMIC_RELAXED, __HIP_MEMORY_SCOPE_AGENT);
}
__device__ __forceinline__ void fstore(unsigned* p, unsigned v) {
  __hip_atomic_store(p, v, __ATOMIC_RELAXED, __HIP_MEMORY_SCOPE_AGENT);
}

__global__ __launch_bounds__(64) void wave_pk(
    float* __restrict__ f0c, float* __restrict__ f0p,   // pair 0 (even-phase writes)
    float* __restrict__ f1c, float* __restrict__ f1p,   // pair 1 (odd-phase writes)
    const float* __restrict__ vp, const float* __restrict__ xwav,
    const int* __restrict__ src_z, const int* __restrict__ src_x,
    const int* __restrict__ rec_z, const int* __restrict__ rec_x,
    float* __restrict__ out,                            // [NSHOTS*NT*NRECS]
    unsigned* __restrict__ bar)                         // wFlag[NTILES] @128B
{
  const int bid  = blockIdx.x;          // one wave per WG, one tile per wave
  const int s    = bid >> 8;
  const int tz   = (bid >> 3) & 31;
  const int tx   = bid & 7;
  const int lane = threadIdx.x;

  const int gz0 = tz * TZ - KSTEPS;     // ext origin
  const int gx0 = tx * XI - HALOX;
  const int gx  = gx0 + lane;
  const bool haloLane = (lane < HALOX) || (lane >= HALOX + XI);
  const bool xok = (unsigned)gx < (unsigned)NX;
  const int off0 = (s * NZ + gz0) * NX + gx;

  // per-ext-row in-domain bits
  unsigned okBits = 0;
  #pragma unroll
  for (int i = 0; i < EXTZ; ++i)
    if (xok && (unsigned)(gz0 + i) < (unsigned)NZ) okBits |= 1u << i;

  // coefficients (c2, d2=2-4c2) and field registers; out-of-domain rows get
  // c2=0 -> p' = 2p - pprev keeps them exactly 0 (matches zero-pad reference)
  v2f c22[NPR], d22[NPR], a2[NPR], b2[NPR];
  #pragma unroll
  for (int p = 0; p < NPR; ++p) {
    #pragma unroll
    for (int h = 0; h < 2; ++h) {
      const int i = 2 * p + h;
      float v = ((okBits >> i) & 1) ? vp[(gz0 + i) * NX + gx] : 0.0f;
      v *= DTf;
      const float c2 = v * v * INVDH2;
      if (h == 0) { c22[p].x = c2; d22[p].x = 2.0f - 4.0f * c2; }
      else        { c22[p].y = c2; d22[p].y = 2.0f - 4.0f * c2; }
    }
    a2[p] = (v2f)(0.0f); b2[p] = (v2f)(0.0f);
  }

  // source mask (redundant injection anywhere in my ext region, so halo
  // evolution matches the owning tile); hasSrc is wave-uniform
  const int slz = src_z[s] - gz0;
  const int slx = src_x[s] - gx0;
  const bool hasSrc = ((unsigned)slz < (unsigned)EXTZ) &&
                      ((unsigned)slx < 64u);
  v2f srcM2[NPR];
  #pragma unroll
  for (int p = 0; p < NPR; ++p) {
    srcM2[p].x = (slx == lane && slz == 2 * p)     ? 1.0f : 0.0f;
    srcM2[p].y = (slx == lane && slz == 2 * p + 1) ? 1.0f : 0.0f;
  }

  // receiver ownership: each rec point belongs to exactly one thread
  // (its interior column). 2 fast packed slots + general overflow bitmask.
  const int gzi0 = tz * TZ;
  unsigned e0 = 0, e1 = 0, rB0 = 0, rB1 = 0, rB2 = 0, rB3 = 0;
  int cnt = 0;
  #pragma unroll 1
  for (int r = 0; r < NRECS; ++r) {
    const int rz = rec_z[s * NRECS + r];
    const int rx = rec_x[s * NRECS + r];
    const int row = rz - gzi0;
    if (!haloLane && rx == gx && (unsigned)row < (unsigned)TZ) {
      const unsigned e = (unsigned)r | ((unsigned)row << 8) | 0x8000u;
      if (cnt == 0) e0 = e;
      else if (cnt == 1) e1 = e;
      else {
        if (r < 32)       rB0 |= 1u << r;
        else if (r < 64)  rB1 |= 1u << (r - 32);
        else if (r < 96)  rB2 |= 1u << (r - 64);
        else              rB3 |= 1u << (r - 96);
      }
      ++cnt;
    }
  }
  const bool hasOvf = (rB0 | rB1 | rB2 | rB3) != 0;

  // neighbor tile index for poll lanes (lane<8 -> 8 surrounding tiles)
  int nb = -1;
  if (lane < 8) {
    const int k  = (lane < 4) ? lane : lane + 1;   // skip center of 3x3
    const int dz = k / 3 - 1, dx = k % 3 - 1;
    const int qz = tz + dz, qx = tx + dx;
    if ((unsigned)qz < (unsigned)NTZT && (unsigned)qx < (unsigned)NTXT)
      nb = (s << 8) | (qz << 3) | qx;
  }
  unsigned* wF = bar;

  float amp[KSTEPS];

  // select interior row (0..7 -> ext rows 8..15 -> pairs 4..7)
  auto selRow = [](const v2f (&n)[NPR], int row) -> float {
    const int pr = row >> 1;
    float vx = n[4].x, vy = n[4].y;
    vx = (pr == 1) ? n[5].x : vx;  vy = (pr == 1) ? n[5].y : vy;
    vx = (pr == 2) ? n[6].x : vx;  vy = (pr == 2) ? n[6].y : vy;
    vx = (pr == 3) ? n[7].x : vx;  vy = (pr == 3) ? n[7].y : vy;
    return (row & 1) ? vy : vx;
  };

  // one step: pure registers + DPP; z-neighbors are adjacent pairs in-thread
  auto do_step = [&](v2f (&cur)[NPR], v2f (&nxt)[NPR], int tau, int t0) {
    const v2f av = { amp[tau], amp[tau] };
    #pragma unroll
    for (int p = 0; p < NPR; ++p) {
      const float cx = cur[p].x, cy = cur[p].y;
      const float upx = (p == 0)       ? 0.0f : cur[p - 1].y;
      const float dny = (p == NPR - 1) ? 0.0f : cur[p + 1].x;
      v2f ud, lr;
      ud.x = upx + cy;
      ud.y = cx + dny;
      lr.x = nbr_left(cx) + nbr_right(cx);
      lr.y = nbr_left(cy) + nbr_right(cy);
      const v2f sum = ud + lr;
      v2f t = __builtin_elementwise_fma(c22[p], sum, -nxt[p]);
      t = __builtin_elementwise_fma(d22[p], cur[p], t);
      nxt[p] = t;
    }
    if (hasSrc) {                       // wave-uniform; only ~4 tiles/shot pay
      #pragma unroll
      for (int p = 0; p < NPR; ++p)
        nxt[p] = __builtin_elementwise_fma(srcM2[p], av, nxt[p]);
    }
    // receiver stores (off critical path; rare divergence)
    const int t = t0 + tau;
    if (e0 & 0x8000u)
      out[(s * NT + t) * NRECS + (e0 & 127u)] = selRow(nxt, (e0 >> 8) & 7);
    if (e1 & 0x8000u)
      out[(s * NT + t) * NRECS + (e1 & 127u)] = selRow(nxt, (e1 >> 8) & 7);
    if (hasOvf) {                        // >2 recs on one thread: ultra-rare
      #pragma unroll
      for (int wd = 0; wd < 4; ++wd) {
        unsigned m = (wd == 0) ? rB0 : (wd == 1) ? rB1 : (wd == 2) ? rB2 : rB3;
        while (m) {
          const int b = __builtin_ctz(m); m &= m - 1;
          const int r = wd * 32 + b;
          const int row = rec_z[s * NRECS + r] - gzi0;
          out[(s * NT + t) * NRECS + r] = selRow(nxt, row);
        }
      }
    }
  };

  #pragma unroll 1
  for (int ph = 0; ph < NPHASE; ++ph) {
    const int t0 = ph * KSTEPS;

    {
      const float4 v = *(const float4*)(xwav + s * NT + t0);
      const float4 w = *(const float4*)(xwav + s * NT + t0 + 4);
      amp[0] = v.x * DTf * DTf; amp[1] = v.y * DTf * DTf;
      amp[2] = v.z * DTf * DTf; amp[3] = v.w * DTf * DTf;
      amp[4] = w.x * DTf * DTf; amp[5] = w.y * DTf * DTf;
      amp[6] = w.z * DTf * DTf; amp[7] = w.w * DTf * DTf;
    }

    if (ph > 0) {
      // single-flag handshake (protocol proven in R2): wF_nb >= ph certifies
      // the neighbor finished ALL of phase ph-1 (writeback drained AND its
      // reload done) -> covers my data-dep (reload below) and my anti-dep
      // (writeback to pair ph&1 at the end of this phase).
      if (nb >= 0) {
        while (fload(wF + (size_t)nb * LSTRIDE) < (unsigned)ph)
          __builtin_amdgcn_s_sleep(1);
      }
      __asm__ volatile("" ::: "memory");   // no compiler hoist of reload
      const float* rc = (ph & 1) ? f0c : f1c;
      const float* rp = (ph & 1) ? f0p : f1p;
      #pragma unroll
      for (int i = 0; i < EXTZ; ++i) {
        const bool zHalo = (i < KSTEPS) || (i >= KSTEPS + TZ);
        if (zHalo || haloLane) {          // interior lanes keep interior rows
          const bool ok = (okBits >> i) & 1;
          const int off = off0 + i * NX;
          const float cv = ok ? gload(rc + off) : 0.0f;
          const float pv = ok ? gload(rp + off) : 0.0f;
          if (i & 1) { a2[i >> 1].y = cv; b2[i >> 1].y = pv; }
          else       { a2[i >> 1].x = cv; b2[i >> 1].x = pv; }
        }
      }
      // loads -> first use is register data-dep; compiler inserts vmcnt waits
    }

    #pragma unroll
    for (int hh = 0; hh < KSTEPS / 2; ++hh) {
      do_step(a2, b2, 2 * hh,     t0);
      do_step(b2, a2, 2 * hh + 1, t0);
    }
    // after 8 steps: a2 = p(t0+7) (cur), b2 = p(t0+6) (prev); valid on interior

    if (ph != NPHASE - 1) {
      float* wc = (ph & 1) ? f1c : f0c;
      float* wp = (ph & 1) ? f1p : f0p;
      if (!haloLane) {
        #pragma unroll
        for (int i = KSTEPS; i < KSTEPS + TZ; ++i) {
          const int off = off0 + i * NX;
          gstore(wc + off, (i & 1) ? a2[i >> 1].y : a2[i >> 1].x);
          gstore(wp + off, (i & 1) ? b2[i >> 1].y : b2[i >> 1].x);
        }
      }
      __asm__ volatile("" ::: "memory");
      __builtin_amdgcn_s_waitcnt(0);       // all lanes' stores ack'd at LLC
      if (lane == 0) fstore(wF + (size_t)bid * LSTRIDE, (unsigned)(ph + 1));
    }
  }
}

extern "C" void kernel_launch(void* const* d_in, const int* in_sizes, int n_in,
                              void* d_out, int out_size, void* d_ws, size_t ws_size,
                              hipStream_t stream) {
  const float* x     = (const float*)d_in[0];
  const float* vp    = (const float*)d_in[1];
  const int*   src_z = (const int*)d_in[2];
  const int*   src_x = (const int*)d_in[3];
  const int*   rec_z = (const int*)d_in[4];
  const int*   rec_x = (const int*)d_in[5];
  float* out = (float*)d_out;

  float* ws = (float*)d_ws;
  const size_t F = (size_t)NSHOTS * NZ * NX;
  float* f0c = ws;
  float* f0p = ws + F;
  float* f1c = ws + 2 * F;
  float* f1p = ws + 3 * F;
  unsigned* bar = (unsigned*)(ws + 4 * F);

  // zero the wFlag region (1024 tiles, 128B-strided)
  hipMemsetAsync(bar, 0, (size_t)NTILES * LSTRIDE * sizeof(unsigned), stream);

  wave_pk<<<dim3(NTILES), dim3(64), 0, stream>>>(
      f0c, f0p, f1c, f1p, vp, x, src_z, src_x, rec_z, rec_x, out, bar);
}